// Round 13
// baseline (566.721 us; speedup 1.0000x reference)
//
#include <hip/hip_runtime.h>
#include <stdint.h>

#define N_NODES 100000
#define N_EDGES 1200000
#define N_GRAPH 512
#define HID 64

#define NBUCK 391      // ceil(100000/256) buckets of 256 nodes (dst >> 8)
#define BCAP  4096     // per-bucket region capacity (mean 3069, ~18 sigma margin)
#define CHUNK 4096     // edges per k_bin block
#define NBIN  ((N_EDGES + CHUNK - 1) / CHUNK)     // 293 bin blocks
#define NEMB  ((N_NODES * 16 + 255) / 256)        // 6250 embed blocks

// pre jobs: ptab 9216 | elin 3072 | bn 64 | cursor NBUCK | weight-bf16 24576 | gptr N_NODES
#define PRE_W0   (144 * 64 + 3 * 1024 + 64 + NBUCK)
#define PRE_WEND (PRE_W0 + 6 * 4096)
#define PRE_JOBS (PRE_WEND + N_NODES)

typedef __attribute__((ext_vector_type(8))) short bshort8;
typedef __attribute__((ext_vector_type(4))) float f32x4;

// bf16 helpers (RNE pack, shift unpack)
__device__ __forceinline__ unsigned short f2bf(float f) {
    unsigned u = __float_as_uint(f);
    u += 0x7FFF + ((u >> 16) & 1);
    return (unsigned short)(u >> 16);
}
__device__ __forceinline__ float bf2f(unsigned short b) {
    return __uint_as_float((unsigned)b << 16);
}

// ---- precompute: projected node-emb rows; edge-lin tables; folded BN; zero
//      cursors; bf16 weights; graph boundaries ----
__global__ __launch_bounds__(256) void k_pre(
    const float* emb0, const float* emb1, const float* emb2, const float* emb3, const float* emb4,
    const float* proj_w,
    const float* ee1, const float* lw1, const float* lb1,
    const float* ee2, const float* lw2, const float* lb2,
    const float* ee3, const float* lw3, const float* lb3,
    const float* bn_g, const float* bn_b, const float* bn_rm, const float* bn_rv,
    const float* w11, const float* w12, const float* w21, const float* w22,
    const float* w31, const float* w32,
    const int* batch,
    float* ptab, float* elin, float* bnsc, float* bnsh, int* cursor,
    unsigned short* wbf, int* gptr)
{
    int job = blockIdx.x * 256 + threadIdx.x;
    if (job < 144 * 64) {
        int row = job >> 6, c = job & 63;
        const float* emb; int lr, dim, off;
        if (row < 120)      { emb = emb0; lr = row;       dim = 64; off = 0;  }
        else if (row < 130) { emb = emb1; lr = row - 120; dim = 16; off = 64; }
        else if (row < 137) { emb = emb2; lr = row - 130; dim = 8;  off = 80; }
        else if (row < 142) { emb = emb3; lr = row - 137; dim = 8;  off = 88; }
        else                { emb = emb4; lr = row - 142; dim = 4;  off = 96; }
        float s = 0.f;
        for (int d = 0; d < dim; ++d)
            s += emb[lr * dim + d] * proj_w[c * 100 + off + d];
        ptab[row * 64 + c] = s;
    } else if (job < 144 * 64 + 3 * 1024) {
        int j = job - 144 * 64;
        int L = j >> 10; int r = (j >> 6) & 15; int c = j & 63;
        const float* ee = (L == 0) ? ee1 : (L == 1) ? ee2 : ee3;
        const float* lw = (L == 0) ? lw1 : (L == 1) ? lw2 : lw3;
        const float* lb = (L == 0) ? lb1 : (L == 1) ? lb2 : lb3;
        float s = lb[c];
        for (int d = 0; d < 8; ++d) s += ee[r * 8 + d] * lw[c * 8 + d];
        elin[j] = s;
    } else if (job < 144 * 64 + 3 * 1024 + 64) {
        int c = job - (144 * 64 + 3 * 1024);
        float sc = bn_g[c] * rsqrtf(bn_rv[c] + 1e-5f);
        bnsc[c] = sc;
        bnsh[c] = bn_b[c] - bn_rm[c] * sc;
    } else if (job < PRE_W0) {
        cursor[job - (144 * 64 + 3 * 1024 + 64)] = 0;
    } else if (job < PRE_WEND) {
        int j2 = job - PRE_W0;
        int sel = j2 >> 12;          // 0..5 = L*2 + which
        const float* W = (sel == 0) ? w11 : (sel == 1) ? w12 : (sel == 2) ? w21
                       : (sel == 3) ? w22 : (sel == 4) ? w31 : w32;
        wbf[j2] = f2bf(W[j2 & 4095]);
    } else if (job < PRE_JOBS) {
        int n = job - PRE_WEND;
        int b = batch[n];
        int bp = (n == 0) ? -1 : batch[n - 1];
        for (int g = bp + 1; g <= b; ++g) gptr[g] = n;
        if (n == N_NODES - 1) {
            for (int g = b + 1; g <= N_GRAPH; ++g) gptr[g] = N_NODES;
        }
    }
}

// ---- CSR pass 1 + node embedding, merged (overlap independent work) ----
// blocks [0, NBIN): LDS counting-sort of a 4096-edge chunk into bucket regions.
//   payload: src(17b) | hash<<17 (4b) | dst_local<<21 (8b)
// blocks [NBIN, NBIN+NEMB): embedding -> bf16 h2 (per-(n,c) fp expression
//   identical to prior k_embed: bit-exact output).
__global__ __launch_bounds__(256) void k_binembed(const int* __restrict__ ei,
                                                  const int* __restrict__ ea,
                                                  int* __restrict__ cursor,
                                                  int* __restrict__ binned,
                                                  const int* __restrict__ x,
                                                  const float* __restrict__ ptab,
                                                  const float* __restrict__ proj_b,
                                                  unsigned short* __restrict__ h2) {
    __shared__ int pay[CHUNK];
    __shared__ unsigned short bkid[CHUNK];
    __shared__ int hist[NBUCK], inc[NBUCK], tmp[NBUCK], gdelta[NBUCK];
    int t = threadIdx.x;
    if (blockIdx.x >= NBIN) {
        // ---- embed part ----
        int id = (blockIdx.x - NBIN) * 256 + t;
        if (id >= N_NODES * 16) return;
        int n = id >> 4, c4 = (id & 15) << 2;
        const int* xr = x + n * 5;
        int r0 = min(max(xr[0], 0), 119);
        int r1 = 120 + min(max(xr[1], 0), 9);
        int r2 = 130 + min(max(xr[2], 0), 6);
        int r3 = 137 + min(max(xr[3], 0), 4);
        int r4 = 142 + min(max(xr[4], 0), 1);
        ushort4 o;
        #pragma unroll
        for (int k = 0; k < 4; ++k) {
            int c = c4 + k;
            float v = proj_b[c] + ptab[r0 * 64 + c] + ptab[r1 * 64 + c] + ptab[r2 * 64 + c]
                    + ptab[r3 * 64 + c] + ptab[r4 * 64 + c];
            ((unsigned short*)&o)[k] = f2bf(v);
        }
        *(ushort4*)(h2 + n * 64 + c4) = o;
        return;
    }
    // ---- bin part ----
    int e0 = blockIdx.x * CHUNK;
    for (int i = t; i < NBUCK; i += 256) hist[i] = 0;
    __syncthreads();
    int mypay[16], myrb[16];
    #pragma unroll
    for (int j = 0; j < 16; ++j) {
        int e = e0 + j * 256 + t;
        myrb[j] = -1;
        if (e < N_EDGES) {
            int s = ei[e];
            int d = ei[N_EDGES + e];
            int hsh = (ea[e * 3] + 3 * ea[e * 3 + 1] + 7 * ea[e * 3 + 2]) & 15;
            int b = d >> 8;
            mypay[j] = s | (hsh << 17) | ((d & 255) << 21);
            int r = atomicAdd(&hist[b], 1);      // rank < 4096 -> 12 bits
            myrb[j] = r | (b << 12);
        }
    }
    __syncthreads();
    for (int i = t; i < NBUCK; i += 256) inc[i] = hist[i];
    __syncthreads();
    for (int off = 1; off < NBUCK; off <<= 1) {
        for (int i = t; i < NBUCK; i += 256) tmp[i] = inc[i] + ((i >= off) ? inc[i - off] : 0);
        __syncthreads();
        for (int i = t; i < NBUCK; i += 256) inc[i] = tmp[i];
        __syncthreads();
    }
    for (int i = t; i < NBUCK; i += 256) {
        int c = hist[i];
        int gp = c ? atomicAdd(&cursor[i], c) : 0;
        gdelta[i] = i * BCAP + gp - (inc[i] - c);
    }
    __syncthreads();
    #pragma unroll
    for (int j = 0; j < 16; ++j) {
        if (myrb[j] >= 0) {
            int b = myrb[j] >> 12, r = myrb[j] & 0xFFF;
            int slot = (inc[b] - hist[b]) + r;
            pay[slot] = mypay[j];
            bkid[slot] = (unsigned short)b;
        }
    }
    __syncthreads();
    int tot = inc[NBUCK - 1];
    for (int i = t; i < tot; i += 256)
        binned[gdelta[bkid[i]] + i] = pay[i];
}

// ---- CSR pass 2: per-bucket local CSR (bucket-base prefix sum inlined) ----
__global__ __launch_bounds__(256) void k_fin(const int* __restrict__ binned,
                                             const int* __restrict__ cursor,
                                             int* __restrict__ rowptr,
                                             int* __restrict__ epk) {
    __shared__ int h2[256], sc[256], cur[256];
    __shared__ int gbs;
    int b = blockIdx.x, t = threadIdx.x;
    int part = 0;
    for (int i = t; i < b; i += 256) part += cursor[i];
    sc[t] = part;
    __syncthreads();
    for (int off = 128; off > 0; off >>= 1) {
        if (t < off) sc[t] += sc[t + off];
        __syncthreads();
    }
    if (t == 0) gbs = sc[0];
    __syncthreads();
    int gb = gbs;
    int cnt = cursor[b];
    int node0 = b << 8;
    h2[t] = 0;
    __syncthreads();
    const int* bp = binned + b * BCAP;
    for (int i = t; i < cnt; i += 256) atomicAdd(&h2[(bp[i] >> 21) & 255], 1);
    __syncthreads();
    sc[t] = h2[t];
    __syncthreads();
    for (int off = 1; off < 256; off <<= 1) {
        int v = (t >= off) ? sc[t - off] : 0;
        __syncthreads();
        sc[t] += v;
        __syncthreads();
    }
    int ex = sc[t] - h2[t];
    cur[t] = ex;
    int n = node0 + t;
    if (n < N_NODES) rowptr[n] = gb + ex;
    if (b == NBUCK - 1 && t == 0) rowptr[N_NODES] = N_EDGES;
    __syncthreads();
    for (int i = t; i < cnt; i += 256) {
        int p = bp[i];
        int pos = atomicAdd(&cur[(p >> 21) & 255], 1);
        epk[gb + pos] = p & 0x1FFFFF;          // src | hash<<17
    }
}

// ---- FUSED gather + MFMA MLP (round-9 numerics frozen: absmax 1.49e-8).
//      W fragments hoisted above the gather loop (code motion only). ----
__global__ __launch_bounds__(256) void k_gmlp(const unsigned short* __restrict__ h2in,
                                              const float* __restrict__ elinL,
                                              const int* __restrict__ rowptr,
                                              const int* __restrict__ epk,
                                              const float* __restrict__ epsp,
                                              const unsigned short* __restrict__ wbf1,
                                              const float* __restrict__ b1,
                                              const unsigned short* __restrict__ wbf2,
                                              const float* __restrict__ b2,
                                              unsigned short* __restrict__ h2out,
                                              const float* __restrict__ bnsc,
                                              const float* __restrict__ bnsh,
                                              const float* __restrict__ gate_w,
                                              const float* __restrict__ gate_b,
                                              float* __restrict__ gate) {
    __shared__ float es[16 * 64];
    __shared__ unsigned short zb[64 * 72];   // padded stride 72 (bf16)
    __shared__ unsigned short hb[64 * 72];
    int t = threadIdx.x;
    ((float4*)es)[t] = ((const float4*)elinL)[t];
    __syncthreads();
    int row0 = blockIdx.x * 64;
    int lane = t & 63, wv = t >> 6;
    int grp = lane >> 4, lc = lane & 15;
    int c4 = lc << 2;
    int m0 = wv * 16;
    float epsv = 1.f + epsp[0];
    // W fragments (hoisted: issue early, consumed after gather)
    int quad = grp;
    bshort8 w1f[4][2], w2f[4][2];
    #pragma unroll
    for (int nt = 0; nt < 4; ++nt)
        #pragma unroll
        for (int kt = 0; kt < 2; ++kt) {
            w1f[nt][kt] = *(const bshort8*)(wbf1 + (nt * 16 + lc) * 64 + kt * 32 + quad * 8);
            w2f[nt][kt] = *(const bshort8*)(wbf2 + (nt * 16 + lc) * 64 + kt * 32 + quad * 8);
        }
    // ---- gather phase: 16 nodes per wave, z -> zb rows m0..m0+15 ----
    for (int i = 0; i < 16; ++i) {
        int n = row0 + m0 + i;
        float4 acc = make_float4(0.f, 0.f, 0.f, 0.f);
        ushort4 hs = {0, 0, 0, 0};
        if (n < N_NODES) {
            int p0 = rowptr[n], p1 = rowptr[n + 1];   // wave-uniform -> scalar
            int deg = p1 - p0;
            hs = *(const ushort4*)(h2in + n * 64 + c4);
            int nb = min(deg, 64);
            int pkv = (lane < deg) ? epk[p0 + lane] : 0;
            #pragma unroll
            for (int j = 0; j < 8; ++j) {
                int e = grp + j * 4;
                if (e < nb) {
                    int pk = __shfl(pkv, e, 64);
                    ushort4 a = *(const ushort4*)(h2in + (pk & 0x1FFFF) * 64 + c4);
                    float4 ev = *(const float4*)(es + ((pk >> 17) & 15) * 64 + c4);
                    acc.x += fmaxf(bf2f(a.x) + ev.x, 0.f);
                    acc.y += fmaxf(bf2f(a.y) + ev.y, 0.f);
                    acc.z += fmaxf(bf2f(a.z) + ev.z, 0.f);
                    acc.w += fmaxf(bf2f(a.w) + ev.w, 0.f);
                }
            }
            for (int e = grp + 32; e < nb; e += 4) {       // rare deg in (32,64]
                int pk = __shfl(pkv, e, 64);
                ushort4 a = *(const ushort4*)(h2in + (pk & 0x1FFFF) * 64 + c4);
                float4 ev = *(const float4*)(es + ((pk >> 17) & 15) * 64 + c4);
                acc.x += fmaxf(bf2f(a.x) + ev.x, 0.f);
                acc.y += fmaxf(bf2f(a.y) + ev.y, 0.f);
                acc.z += fmaxf(bf2f(a.z) + ev.z, 0.f);
                acc.w += fmaxf(bf2f(a.w) + ev.w, 0.f);
            }
            for (int p = p0 + 64 + grp; p < p1; p += 4) {  // ultra-rare deg > 64
                int pk = epk[p];
                ushort4 a = *(const ushort4*)(h2in + (pk & 0x1FFFF) * 64 + c4);
                float4 ev = *(const float4*)(es + ((pk >> 17) & 15) * 64 + c4);
                acc.x += fmaxf(bf2f(a.x) + ev.x, 0.f);
                acc.y += fmaxf(bf2f(a.y) + ev.y, 0.f);
                acc.z += fmaxf(bf2f(a.z) + ev.z, 0.f);
                acc.w += fmaxf(bf2f(a.w) + ev.w, 0.f);
            }
        }
        acc.x += __shfl_down(acc.x, 32, 64);
        acc.y += __shfl_down(acc.y, 32, 64);
        acc.z += __shfl_down(acc.z, 32, 64);
        acc.w += __shfl_down(acc.w, 32, 64);
        acc.x += __shfl_down(acc.x, 16, 64);
        acc.y += __shfl_down(acc.y, 16, 64);
        acc.z += __shfl_down(acc.z, 16, 64);
        acc.w += __shfl_down(acc.w, 16, 64);
        if (grp == 0) {
            ushort4 zv;
            zv.x = f2bf(epsv * bf2f(hs.x) + acc.x);
            zv.y = f2bf(epsv * bf2f(hs.y) + acc.y);
            zv.z = f2bf(epsv * bf2f(hs.z) + acc.z);
            zv.w = f2bf(epsv * bf2f(hs.w) + acc.w);
            *(ushort4*)(zb + (m0 + i) * 72 + c4) = zv;
        }
    }
    // ---- MFMA phase (wave-local zb/hb) ----
    bshort8 a0 = *(const bshort8*)(zb + (m0 + lc) * 72 + quad * 8);
    bshort8 a1 = *(const bshort8*)(zb + (m0 + lc) * 72 + 32 + quad * 8);
    f32x4 acc1[4];
    #pragma unroll
    for (int nt = 0; nt < 4; ++nt) {
        acc1[nt] = (f32x4){0.f, 0.f, 0.f, 0.f};
        acc1[nt] = __builtin_amdgcn_mfma_f32_16x16x32_bf16(a0, w1f[nt][0], acc1[nt], 0, 0, 0);
        acc1[nt] = __builtin_amdgcn_mfma_f32_16x16x32_bf16(a1, w1f[nt][1], acc1[nt], 0, 0, 0);
    }
    #pragma unroll
    for (int nt = 0; nt < 4; ++nt) {
        float bb = b1[nt * 16 + lc];
        #pragma unroll
        for (int reg = 0; reg < 4; ++reg) {
            float v = fmaxf(acc1[nt][reg] + bb, 0.f);
            hb[(m0 + quad * 4 + reg) * 72 + nt * 16 + lc] = f2bf(v);
        }
    }
    bshort8 c0 = *(const bshort8*)(hb + (m0 + lc) * 72 + quad * 8);
    bshort8 c1 = *(const bshort8*)(hb + (m0 + lc) * 72 + 32 + quad * 8);
    f32x4 acc2[4];
    #pragma unroll
    for (int nt = 0; nt < 4; ++nt) {
        acc2[nt] = (f32x4){0.f, 0.f, 0.f, 0.f};
        acc2[nt] = __builtin_amdgcn_mfma_f32_16x16x32_bf16(c0, w2f[nt][0], acc2[nt], 0, 0, 0);
        acc2[nt] = __builtin_amdgcn_mfma_f32_16x16x32_bf16(c1, w2f[nt][1], acc2[nt], 0, 0, 0);
    }
    if (gate == nullptr) {
        #pragma unroll
        for (int reg = 0; reg < 4; ++reg) {
            int gr = row0 + m0 + quad * 4 + reg;
            if (gr < N_NODES) {
                #pragma unroll
                for (int nt = 0; nt < 4; ++nt) {
                    int col = nt * 16 + lc;
                    float v = fmaxf(acc2[nt][reg] + b2[col], 0.f);
                    h2out[gr * 64 + col] = f2bf(v);
                }
            }
        }
    } else {
        float gb = gate_b[0];
        #pragma unroll
        for (int reg = 0; reg < 4; ++reg) {
            int gr = row0 + m0 + quad * 4 + reg;
            float p = 0.f;
            #pragma unroll
            for (int nt = 0; nt < 4; ++nt) {
                int col = nt * 16 + lc;
                float v = fmaxf(acc2[nt][reg] + b2[col], 0.f) * bnsc[col] + bnsh[col];
                p += v * gate_w[col];
                if (gr < N_NODES) h2out[gr * 64 + col] = f2bf(v);
            }
            p += __shfl_down(p, 8, 16);
            p += __shfl_down(p, 4, 16);
            p += __shfl_down(p, 2, 16);
            p += __shfl_down(p, 1, 16);
            if (lc == 0 && gr < N_NODES) gate[gr] = p + gb;
        }
    }
}

// ---- attention aggregation + readout head, one block per graph ----
__global__ __launch_bounds__(256) void k_att(const unsigned short* __restrict__ h2,
                                             const float* __restrict__ gate,
                                             const int* __restrict__ gptr,
                                             const float* __restrict__ hw1,
                                             const float* __restrict__ hb1,
                                             const float* __restrict__ hw2,
                                             const float* __restrict__ hb2,
                                             float* __restrict__ out) {
    __shared__ float red[4];
    __shared__ float acc_s[4][64];
    __shared__ float gvec[64];
    __shared__ float m_s, den_s;
    int t = threadIdx.x, g = blockIdx.x;
    int n0 = gptr[g], n1 = gptr[g + 1];
    float m = -INFINITY;
    for (int n = n0 + t; n < n1; n += 256) m = fmaxf(m, gate[n]);
    #pragma unroll
    for (int off = 32; off > 0; off >>= 1) m = fmaxf(m, __shfl_down(m, off, 64));
    if ((t & 63) == 0) red[t >> 6] = m;
    __syncthreads();
    if (t == 0) m_s = fmaxf(fmaxf(red[0], red[1]), fmaxf(red[2], red[3]));
    __syncthreads();
    m = m_s;
    float s = 0.f;
    for (int n = n0 + t; n < n1; n += 256) s += expf(gate[n] - m);
    #pragma unroll
    for (int off = 32; off > 0; off >>= 1) s += __shfl_down(s, off, 64);
    if ((t & 63) == 0) red[t >> 6] = s;
    __syncthreads();
    if (t == 0) den_s = red[0] + red[1] + red[2] + red[3] + 1e-16f;
    __syncthreads();
    float invden = 1.f / den_s;
    int c = t & 63, w = t >> 6;
    float acc = 0.f;
    for (int n = n0 + w; n < n1; n += 4) {
        float a = expf(gate[n] - m);
        acc += a * bf2f(h2[n * 64 + c]);
    }
    acc_s[w][c] = acc;
    __syncthreads();
    if (w == 0)
        gvec[c] = (acc_s[0][c] + acc_s[1][c] + acc_s[2][c] + acc_s[3][c]) * invden;
    __syncthreads();
    float p = 0.f;
    if (t < 128) {
        float sh = hb1[t];
        const float* wr = hw1 + t * 64;
        #pragma unroll
        for (int k = 0; k < 64; ++k) sh += gvec[k] * wr[k];
        p = fmaxf(sh, 0.f) * hw2[t];
    }
    #pragma unroll
    for (int off = 32; off > 0; off >>= 1) p += __shfl_down(p, off, 64);
    if (t == 0) red[0] = p;
    if (t == 64) red[1] = p;
    __syncthreads();
    if (t == 0) out[g] = red[0] + red[1] + hb2[0];
}

extern "C" void kernel_launch(void* const* d_in, const int* in_sizes, int n_in,
                              void* d_out, int out_size, void* d_ws, size_t ws_size,
                              hipStream_t stream) {
    const int* x    = (const int*)d_in[0];
    const int* ei   = (const int*)d_in[1];
    const int* ea   = (const int*)d_in[2];
    const int* bat  = (const int*)d_in[3];
    const float* emb0 = (const float*)d_in[4];
    const float* emb1 = (const float*)d_in[5];
    const float* emb2 = (const float*)d_in[6];
    const float* emb3 = (const float*)d_in[7];
    const float* emb4 = (const float*)d_in[8];
    const float* proj_w = (const float*)d_in[9];
    const float* proj_b = (const float*)d_in[10];
    const float* bn_g  = (const float*)d_in[35];
    const float* bn_b  = (const float*)d_in[36];
    const float* bn_rm = (const float*)d_in[37];
    const float* bn_rv = (const float*)d_in[38];
    const float* gate_w = (const float*)d_in[39];
    const float* gate_b = (const float*)d_in[40];
    const float* head_w1 = (const float*)d_in[41];
    const float* head_b1 = (const float*)d_in[42];
    const float* head_w2 = (const float*)d_in[43];
    const float* head_b2 = (const float*)d_in[44];

    char* wsb = (char*)d_ws;
    size_t o = 0;
    auto alloc = [&](size_t bytes) -> void* {
        void* p = wsb + o;
        o += (bytes + 255) & ~(size_t)255;
        return p;
    };
    float* ptab   = (float*)alloc(144 * 64 * 4);
    float* elin   = (float*)alloc(3 * 16 * 64 * 4);
    float* bnsc   = (float*)alloc(64 * 4);
    float* bnsh   = (float*)alloc(64 * 4);
    int* cursor   = (int*)alloc(NBUCK * 4);
    int* gptr     = (int*)alloc((N_GRAPH + 1) * 4);
    int* rowptr   = (int*)alloc(((size_t)N_NODES + 1) * 4);
    int* binned   = (int*)alloc((size_t)NBUCK * BCAP * 4);
    int* epk      = (int*)alloc((size_t)N_EDGES * 4);
    unsigned short* h2a = (unsigned short*)alloc((size_t)N_NODES * 64 * 2);
    unsigned short* h2b = (unsigned short*)alloc((size_t)N_NODES * 64 * 2);
    float* gate   = (float*)alloc((size_t)N_NODES * 4);
    unsigned short* wbf = (unsigned short*)alloc(6 * 4096 * 2);

    k_pre<<<(PRE_JOBS + 255) / 256, 256, 0, stream>>>(
                                  emb0, emb1, emb2, emb3, emb4, proj_w,
                                  (const float*)d_in[11], (const float*)d_in[12], (const float*)d_in[13],
                                  (const float*)d_in[19], (const float*)d_in[20], (const float*)d_in[21],
                                  (const float*)d_in[27], (const float*)d_in[28], (const float*)d_in[29],
                                  bn_g, bn_b, bn_rm, bn_rv,
                                  (const float*)d_in[15], (const float*)d_in[17],
                                  (const float*)d_in[23], (const float*)d_in[25],
                                  (const float*)d_in[31], (const float*)d_in[33],
                                  bat,
                                  ptab, elin, bnsc, bnsh, cursor, wbf, gptr);
    k_binembed<<<NBIN + NEMB, 256, 0, stream>>>(ei, ea, cursor, binned, x, ptab, proj_b, h2a);
    k_fin<<<NBUCK, 256, 0, stream>>>(binned, cursor, rowptr, epk);

    unsigned short* hin = h2a;
    unsigned short* hout = h2b;
    for (int L = 0; L < 3; ++L) {
        const float* epsp = (const float*)d_in[14 + L * 8];
        const float* b1   = (const float*)d_in[16 + L * 8];
        const float* b2   = (const float*)d_in[18 + L * 8];
        const unsigned short* wb1 = wbf + (L * 2 + 0) * 4096;
        const unsigned short* wb2 = wbf + (L * 2 + 1) * 4096;
        if (L < 2) {
            k_gmlp<<<(N_NODES + 63) / 64, 256, 0, stream>>>(hin, elin + L * 1024, rowptr, epk,
                                                            epsp, wb1, b1, wb2, b2, hout,
                                                            nullptr, nullptr, nullptr, nullptr,
                                                            nullptr);
        } else {
            k_gmlp<<<(N_NODES + 63) / 64, 256, 0, stream>>>(hin, elin + L * 1024, rowptr, epk,
                                                            epsp, wb1, b1, wb2, b2, hout,
                                                            bnsc, bnsh, gate_w, gate_b, gate);
        }
        unsigned short* tmp = hin; hin = hout; hout = tmp;
    }

    // after 3 swaps: hin points at the final (layer-3) output buffer
    k_att<<<N_GRAPH, 256, 0, stream>>>(hin, gate, gptr, head_w1, head_b1, head_w2, head_b2,
                                       (float*)d_out);
}

// Round 14
// 380.935 us; speedup vs baseline: 1.4877x; 1.4877x over previous
//
#include <hip/hip_runtime.h>
#include <stdint.h>

#define N_NODES 100000
#define N_EDGES 1200000
#define N_GRAPH 512
#define HID 64

#define NBUCK 391      // ceil(100000/256) buckets of 256 nodes (dst >> 8)
#define BCAP  4096     // per-bucket region capacity (mean 3069, ~18 sigma margin)
#define CHUNK 4096     // edges per k_bin block
#define NBIN  ((N_EDGES + CHUNK - 1) / CHUNK)     // 293 bin blocks
#define NEMB  ((N_NODES * 16 + 255) / 256)        // 6250 embed blocks

// pre jobs: ptab 9216 | elin 3072 | bn 64 | cursor NBUCK | weight-bf16 24576 | gptr N_NODES
#define PRE_W0   (144 * 64 + 3 * 1024 + 64 + NBUCK)
#define PRE_WEND (PRE_W0 + 6 * 4096)
#define PRE_JOBS (PRE_WEND + N_NODES)

typedef __attribute__((ext_vector_type(8))) short bshort8;
typedef __attribute__((ext_vector_type(4))) float f32x4;

// bf16 helpers (RNE pack, shift unpack)
__device__ __forceinline__ unsigned short f2bf(float f) {
    unsigned u = __float_as_uint(f);
    u += 0x7FFF + ((u >> 16) & 1);
    return (unsigned short)(u >> 16);
}
__device__ __forceinline__ float bf2f(unsigned short b) {
    return __uint_as_float((unsigned)b << 16);
}

// ---- precompute: projected node-emb rows; edge-lin tables; folded BN; zero
//      cursors; bf16 weights; graph boundaries ----
__global__ __launch_bounds__(256) void k_pre(
    const float* emb0, const float* emb1, const float* emb2, const float* emb3, const float* emb4,
    const float* proj_w,
    const float* ee1, const float* lw1, const float* lb1,
    const float* ee2, const float* lw2, const float* lb2,
    const float* ee3, const float* lw3, const float* lb3,
    const float* bn_g, const float* bn_b, const float* bn_rm, const float* bn_rv,
    const float* w11, const float* w12, const float* w21, const float* w22,
    const float* w31, const float* w32,
    const int* batch,
    float* ptab, float* elin, float* bnsc, float* bnsh, int* cursor,
    unsigned short* wbf, int* gptr)
{
    int job = blockIdx.x * 256 + threadIdx.x;
    if (job < 144 * 64) {
        int row = job >> 6, c = job & 63;
        const float* emb; int lr, dim, off;
        if (row < 120)      { emb = emb0; lr = row;       dim = 64; off = 0;  }
        else if (row < 130) { emb = emb1; lr = row - 120; dim = 16; off = 64; }
        else if (row < 137) { emb = emb2; lr = row - 130; dim = 8;  off = 80; }
        else if (row < 142) { emb = emb3; lr = row - 137; dim = 8;  off = 88; }
        else                { emb = emb4; lr = row - 142; dim = 4;  off = 96; }
        float s = 0.f;
        for (int d = 0; d < dim; ++d)
            s += emb[lr * dim + d] * proj_w[c * 100 + off + d];
        ptab[row * 64 + c] = s;
    } else if (job < 144 * 64 + 3 * 1024) {
        int j = job - 144 * 64;
        int L = j >> 10; int r = (j >> 6) & 15; int c = j & 63;
        const float* ee = (L == 0) ? ee1 : (L == 1) ? ee2 : ee3;
        const float* lw = (L == 0) ? lw1 : (L == 1) ? lw2 : lw3;
        const float* lb = (L == 0) ? lb1 : (L == 1) ? lb2 : lb3;
        float s = lb[c];
        for (int d = 0; d < 8; ++d) s += ee[r * 8 + d] * lw[c * 8 + d];
        elin[j] = s;
    } else if (job < 144 * 64 + 3 * 1024 + 64) {
        int c = job - (144 * 64 + 3 * 1024);
        float sc = bn_g[c] * rsqrtf(bn_rv[c] + 1e-5f);
        bnsc[c] = sc;
        bnsh[c] = bn_b[c] - bn_rm[c] * sc;
    } else if (job < PRE_W0) {
        cursor[job - (144 * 64 + 3 * 1024 + 64)] = 0;
    } else if (job < PRE_WEND) {
        int j2 = job - PRE_W0;
        int sel = j2 >> 12;          // 0..5 = L*2 + which
        const float* W = (sel == 0) ? w11 : (sel == 1) ? w12 : (sel == 2) ? w21
                       : (sel == 3) ? w22 : (sel == 4) ? w31 : w32;
        wbf[j2] = f2bf(W[j2 & 4095]);
    } else if (job < PRE_JOBS) {
        int n = job - PRE_WEND;
        int b = batch[n];
        int bp = (n == 0) ? -1 : batch[n - 1];
        for (int g = bp + 1; g <= b; ++g) gptr[g] = n;
        if (n == N_NODES - 1) {
            for (int g = b + 1; g <= N_GRAPH; ++g) gptr[g] = N_NODES;
        }
    }
}

// ---- CSR pass 1 + node embedding, merged (overlap independent work) ----
__global__ __launch_bounds__(256) void k_binembed(const int* __restrict__ ei,
                                                  const int* __restrict__ ea,
                                                  int* __restrict__ cursor,
                                                  int* __restrict__ binned,
                                                  const int* __restrict__ x,
                                                  const float* __restrict__ ptab,
                                                  const float* __restrict__ proj_b,
                                                  unsigned short* __restrict__ h2) {
    __shared__ int pay[CHUNK];
    __shared__ unsigned short bkid[CHUNK];
    __shared__ int hist[NBUCK], inc[NBUCK], tmp[NBUCK], gdelta[NBUCK];
    int t = threadIdx.x;
    if (blockIdx.x >= NBIN) {
        // ---- embed part ----
        int id = (blockIdx.x - NBIN) * 256 + t;
        if (id >= N_NODES * 16) return;
        int n = id >> 4, c4 = (id & 15) << 2;
        const int* xr = x + n * 5;
        int r0 = min(max(xr[0], 0), 119);
        int r1 = 120 + min(max(xr[1], 0), 9);
        int r2 = 130 + min(max(xr[2], 0), 6);
        int r3 = 137 + min(max(xr[3], 0), 4);
        int r4 = 142 + min(max(xr[4], 0), 1);
        ushort4 o;
        #pragma unroll
        for (int k = 0; k < 4; ++k) {
            int c = c4 + k;
            float v = proj_b[c] + ptab[r0 * 64 + c] + ptab[r1 * 64 + c] + ptab[r2 * 64 + c]
                    + ptab[r3 * 64 + c] + ptab[r4 * 64 + c];
            ((unsigned short*)&o)[k] = f2bf(v);
        }
        *(ushort4*)(h2 + n * 64 + c4) = o;
        return;
    }
    // ---- bin part ----
    int e0 = blockIdx.x * CHUNK;
    for (int i = t; i < NBUCK; i += 256) hist[i] = 0;
    __syncthreads();
    int mypay[16], myrb[16];
    #pragma unroll
    for (int j = 0; j < 16; ++j) {
        int e = e0 + j * 256 + t;
        myrb[j] = -1;
        if (e < N_EDGES) {
            int s = ei[e];
            int d = ei[N_EDGES + e];
            int hsh = (ea[e * 3] + 3 * ea[e * 3 + 1] + 7 * ea[e * 3 + 2]) & 15;
            int b = d >> 8;
            mypay[j] = s | (hsh << 17) | ((d & 255) << 21);
            int r = atomicAdd(&hist[b], 1);      // rank < 4096 -> 12 bits
            myrb[j] = r | (b << 12);
        }
    }
    __syncthreads();
    for (int i = t; i < NBUCK; i += 256) inc[i] = hist[i];
    __syncthreads();
    for (int off = 1; off < NBUCK; off <<= 1) {
        for (int i = t; i < NBUCK; i += 256) tmp[i] = inc[i] + ((i >= off) ? inc[i - off] : 0);
        __syncthreads();
        for (int i = t; i < NBUCK; i += 256) inc[i] = tmp[i];
        __syncthreads();
    }
    for (int i = t; i < NBUCK; i += 256) {
        int c = hist[i];
        int gp = c ? atomicAdd(&cursor[i], c) : 0;
        gdelta[i] = i * BCAP + gp - (inc[i] - c);
    }
    __syncthreads();
    #pragma unroll
    for (int j = 0; j < 16; ++j) {
        if (myrb[j] >= 0) {
            int b = myrb[j] >> 12, r = myrb[j] & 0xFFF;
            int slot = (inc[b] - hist[b]) + r;
            pay[slot] = mypay[j];
            bkid[slot] = (unsigned short)b;
        }
    }
    __syncthreads();
    int tot = inc[NBUCK - 1];
    for (int i = t; i < tot; i += 256)
        binned[gdelta[bkid[i]] + i] = pay[i];
}

// ---- CSR pass 2: per-bucket local CSR (bucket-base prefix sum inlined) ----
__global__ __launch_bounds__(256) void k_fin(const int* __restrict__ binned,
                                             const int* __restrict__ cursor,
                                             int* __restrict__ rowptr,
                                             int* __restrict__ epk) {
    __shared__ int h2[256], sc[256], cur[256];
    __shared__ int gbs;
    int b = blockIdx.x, t = threadIdx.x;
    int part = 0;
    for (int i = t; i < b; i += 256) part += cursor[i];
    sc[t] = part;
    __syncthreads();
    for (int off = 128; off > 0; off >>= 1) {
        if (t < off) sc[t] += sc[t + off];
        __syncthreads();
    }
    if (t == 0) gbs = sc[0];
    __syncthreads();
    int gb = gbs;
    int cnt = cursor[b];
    int node0 = b << 8;
    h2[t] = 0;
    __syncthreads();
    const int* bp = binned + b * BCAP;
    for (int i = t; i < cnt; i += 256) atomicAdd(&h2[(bp[i] >> 21) & 255], 1);
    __syncthreads();
    sc[t] = h2[t];
    __syncthreads();
    for (int off = 1; off < 256; off <<= 1) {
        int v = (t >= off) ? sc[t - off] : 0;
        __syncthreads();
        sc[t] += v;
        __syncthreads();
    }
    int ex = sc[t] - h2[t];
    cur[t] = ex;
    int n = node0 + t;
    if (n < N_NODES) rowptr[n] = gb + ex;
    if (b == NBUCK - 1 && t == 0) rowptr[N_NODES] = N_EDGES;
    __syncthreads();
    for (int i = t; i < cnt; i += 256) {
        int p = bp[i];
        int pos = atomicAdd(&cur[(p >> 21) & 255], 1);
        epk[gb + pos] = p & 0x1FFFFF;          // src | hash<<17
    }
}

// ---- FUSED gather + MFMA MLP (round-12 verbatim: W frags loaded AFTER gather,
//      36 VGPR / 53% occupancy; numerics frozen, absmax 1.490116e-8) ----
__global__ __launch_bounds__(256) void k_gmlp(const unsigned short* __restrict__ h2in,
                                              const float* __restrict__ elinL,
                                              const int* __restrict__ rowptr,
                                              const int* __restrict__ epk,
                                              const float* __restrict__ epsp,
                                              const unsigned short* __restrict__ wbf1,
                                              const float* __restrict__ b1,
                                              const unsigned short* __restrict__ wbf2,
                                              const float* __restrict__ b2,
                                              unsigned short* __restrict__ h2out,
                                              const float* __restrict__ bnsc,
                                              const float* __restrict__ bnsh,
                                              const float* __restrict__ gate_w,
                                              const float* __restrict__ gate_b,
                                              float* __restrict__ gate) {
    __shared__ float es[16 * 64];
    __shared__ unsigned short zb[64 * 72];   // padded stride 72 (bf16)
    __shared__ unsigned short hb[64 * 72];
    int t = threadIdx.x;
    ((float4*)es)[t] = ((const float4*)elinL)[t];
    __syncthreads();
    int row0 = blockIdx.x * 64;
    int lane = t & 63, wv = t >> 6;
    int grp = lane >> 4, lc = lane & 15;
    int c4 = lc << 2;
    int m0 = wv * 16;
    float epsv = 1.f + epsp[0];
    // ---- gather phase: 16 nodes per wave, z -> zb rows m0..m0+15 ----
    for (int i = 0; i < 16; ++i) {
        int n = row0 + m0 + i;
        float4 acc = make_float4(0.f, 0.f, 0.f, 0.f);
        ushort4 hs = {0, 0, 0, 0};
        if (n < N_NODES) {
            int p0 = rowptr[n], p1 = rowptr[n + 1];   // wave-uniform -> scalar
            int deg = p1 - p0;
            hs = *(const ushort4*)(h2in + n * 64 + c4);
            int nb = min(deg, 64);
            int pkv = (lane < deg) ? epk[p0 + lane] : 0;
            #pragma unroll
            for (int j = 0; j < 8; ++j) {
                int e = grp + j * 4;
                if (e < nb) {
                    int pk = __shfl(pkv, e, 64);
                    ushort4 a = *(const ushort4*)(h2in + (pk & 0x1FFFF) * 64 + c4);
                    float4 ev = *(const float4*)(es + ((pk >> 17) & 15) * 64 + c4);
                    acc.x += fmaxf(bf2f(a.x) + ev.x, 0.f);
                    acc.y += fmaxf(bf2f(a.y) + ev.y, 0.f);
                    acc.z += fmaxf(bf2f(a.z) + ev.z, 0.f);
                    acc.w += fmaxf(bf2f(a.w) + ev.w, 0.f);
                }
            }
            for (int e = grp + 32; e < nb; e += 4) {       // rare deg in (32,64]
                int pk = __shfl(pkv, e, 64);
                ushort4 a = *(const ushort4*)(h2in + (pk & 0x1FFFF) * 64 + c4);
                float4 ev = *(const float4*)(es + ((pk >> 17) & 15) * 64 + c4);
                acc.x += fmaxf(bf2f(a.x) + ev.x, 0.f);
                acc.y += fmaxf(bf2f(a.y) + ev.y, 0.f);
                acc.z += fmaxf(bf2f(a.z) + ev.z, 0.f);
                acc.w += fmaxf(bf2f(a.w) + ev.w, 0.f);
            }
            for (int p = p0 + 64 + grp; p < p1; p += 4) {  // ultra-rare deg > 64
                int pk = epk[p];
                ushort4 a = *(const ushort4*)(h2in + (pk & 0x1FFFF) * 64 + c4);
                float4 ev = *(const float4*)(es + ((pk >> 17) & 15) * 64 + c4);
                acc.x += fmaxf(bf2f(a.x) + ev.x, 0.f);
                acc.y += fmaxf(bf2f(a.y) + ev.y, 0.f);
                acc.z += fmaxf(bf2f(a.z) + ev.z, 0.f);
                acc.w += fmaxf(bf2f(a.w) + ev.w, 0.f);
            }
        }
        acc.x += __shfl_down(acc.x, 32, 64);
        acc.y += __shfl_down(acc.y, 32, 64);
        acc.z += __shfl_down(acc.z, 32, 64);
        acc.w += __shfl_down(acc.w, 32, 64);
        acc.x += __shfl_down(acc.x, 16, 64);
        acc.y += __shfl_down(acc.y, 16, 64);
        acc.z += __shfl_down(acc.z, 16, 64);
        acc.w += __shfl_down(acc.w, 16, 64);
        if (grp == 0) {
            ushort4 zv;
            zv.x = f2bf(epsv * bf2f(hs.x) + acc.x);
            zv.y = f2bf(epsv * bf2f(hs.y) + acc.y);
            zv.z = f2bf(epsv * bf2f(hs.z) + acc.z);
            zv.w = f2bf(epsv * bf2f(hs.w) + acc.w);
            *(ushort4*)(zb + (m0 + i) * 72 + c4) = zv;
        }
    }
    // ---- MFMA phase (wave-local zb/hb; W frags loaded NOW — keeps gather-phase
    //      VGPRs low; r13 hoist experiment: 68 VGPR -> 24% occ -> 2.1x slower) ----
    int quad = grp;
    bshort8 w1f[4][2], w2f[4][2];
    #pragma unroll
    for (int nt = 0; nt < 4; ++nt)
        #pragma unroll
        for (int kt = 0; kt < 2; ++kt) {
            w1f[nt][kt] = *(const bshort8*)(wbf1 + (nt * 16 + lc) * 64 + kt * 32 + quad * 8);
            w2f[nt][kt] = *(const bshort8*)(wbf2 + (nt * 16 + lc) * 64 + kt * 32 + quad * 8);
        }
    bshort8 a0 = *(const bshort8*)(zb + (m0 + lc) * 72 + quad * 8);
    bshort8 a1 = *(const bshort8*)(zb + (m0 + lc) * 72 + 32 + quad * 8);
    f32x4 acc1[4];
    #pragma unroll
    for (int nt = 0; nt < 4; ++nt) {
        acc1[nt] = (f32x4){0.f, 0.f, 0.f, 0.f};
        acc1[nt] = __builtin_amdgcn_mfma_f32_16x16x32_bf16(a0, w1f[nt][0], acc1[nt], 0, 0, 0);
        acc1[nt] = __builtin_amdgcn_mfma_f32_16x16x32_bf16(a1, w1f[nt][1], acc1[nt], 0, 0, 0);
    }
    #pragma unroll
    for (int nt = 0; nt < 4; ++nt) {
        float bb = b1[nt * 16 + lc];
        #pragma unroll
        for (int reg = 0; reg < 4; ++reg) {
            float v = fmaxf(acc1[nt][reg] + bb, 0.f);
            hb[(m0 + quad * 4 + reg) * 72 + nt * 16 + lc] = f2bf(v);
        }
    }
    bshort8 c0 = *(const bshort8*)(hb + (m0 + lc) * 72 + quad * 8);
    bshort8 c1 = *(const bshort8*)(hb + (m0 + lc) * 72 + 32 + quad * 8);
    f32x4 acc2[4];
    #pragma unroll
    for (int nt = 0; nt < 4; ++nt) {
        acc2[nt] = (f32x4){0.f, 0.f, 0.f, 0.f};
        acc2[nt] = __builtin_amdgcn_mfma_f32_16x16x32_bf16(c0, w2f[nt][0], acc2[nt], 0, 0, 0);
        acc2[nt] = __builtin_amdgcn_mfma_f32_16x16x32_bf16(c1, w2f[nt][1], acc2[nt], 0, 0, 0);
    }
    if (gate == nullptr) {
        #pragma unroll
        for (int reg = 0; reg < 4; ++reg) {
            int gr = row0 + m0 + quad * 4 + reg;
            if (gr < N_NODES) {
                #pragma unroll
                for (int nt = 0; nt < 4; ++nt) {
                    int col = nt * 16 + lc;
                    float v = fmaxf(acc2[nt][reg] + b2[col], 0.f);
                    h2out[gr * 64 + col] = f2bf(v);
                }
            }
        }
    } else {
        float gb = gate_b[0];
        #pragma unroll
        for (int reg = 0; reg < 4; ++reg) {
            int gr = row0 + m0 + quad * 4 + reg;
            float p = 0.f;
            #pragma unroll
            for (int nt = 0; nt < 4; ++nt) {
                int col = nt * 16 + lc;
                float v = fmaxf(acc2[nt][reg] + b2[col], 0.f) * bnsc[col] + bnsh[col];
                p += v * gate_w[col];
                if (gr < N_NODES) h2out[gr * 64 + col] = f2bf(v);
            }
            p += __shfl_down(p, 8, 16);
            p += __shfl_down(p, 4, 16);
            p += __shfl_down(p, 2, 16);
            p += __shfl_down(p, 1, 16);
            if (lc == 0 && gr < N_NODES) gate[gr] = p + gb;
        }
    }
}

// ---- attention aggregation + readout head, one block per graph ----
__global__ __launch_bounds__(256) void k_att(const unsigned short* __restrict__ h2,
                                             const float* __restrict__ gate,
                                             const int* __restrict__ gptr,
                                             const float* __restrict__ hw1,
                                             const float* __restrict__ hb1,
                                             const float* __restrict__ hw2,
                                             const float* __restrict__ hb2,
                                             float* __restrict__ out) {
    __shared__ float red[4];
    __shared__ float acc_s[4][64];
    __shared__ float gvec[64];
    __shared__ float m_s, den_s;
    int t = threadIdx.x, g = blockIdx.x;
    int n0 = gptr[g], n1 = gptr[g + 1];
    float m = -INFINITY;
    for (int n = n0 + t; n < n1; n += 256) m = fmaxf(m, gate[n]);
    #pragma unroll
    for (int off = 32; off > 0; off >>= 1) m = fmaxf(m, __shfl_down(m, off, 64));
    if ((t & 63) == 0) red[t >> 6] = m;
    __syncthreads();
    if (t == 0) m_s = fmaxf(fmaxf(red[0], red[1]), fmaxf(red[2], red[3]));
    __syncthreads();
    m = m_s;
    float s = 0.f;
    for (int n = n0 + t; n < n1; n += 256) s += expf(gate[n] - m);
    #pragma unroll
    for (int off = 32; off > 0; off >>= 1) s += __shfl_down(s, off, 64);
    if ((t & 63) == 0) red[t >> 6] = s;
    __syncthreads();
    if (t == 0) den_s = red[0] + red[1] + red[2] + red[3] + 1e-16f;
    __syncthreads();
    float invden = 1.f / den_s;
    int c = t & 63, w = t >> 6;
    float acc = 0.f;
    for (int n = n0 + w; n < n1; n += 4) {
        float a = expf(gate[n] - m);
        acc += a * bf2f(h2[n * 64 + c]);
    }
    acc_s[w][c] = acc;
    __syncthreads();
    if (w == 0)
        gvec[c] = (acc_s[0][c] + acc_s[1][c] + acc_s[2][c] + acc_s[3][c]) * invden;
    __syncthreads();
    float p = 0.f;
    if (t < 128) {
        float sh = hb1[t];
        const float* wr = hw1 + t * 64;
        #pragma unroll
        for (int k = 0; k < 64; ++k) sh += gvec[k] * wr[k];
        p = fmaxf(sh, 0.f) * hw2[t];
    }
    #pragma unroll
    for (int off = 32; off > 0; off >>= 1) p += __shfl_down(p, off, 64);
    if (t == 0) red[0] = p;
    if (t == 64) red[1] = p;
    __syncthreads();
    if (t == 0) out[g] = red[0] + red[1] + hb2[0];
}

extern "C" void kernel_launch(void* const* d_in, const int* in_sizes, int n_in,
                              void* d_out, int out_size, void* d_ws, size_t ws_size,
                              hipStream_t stream) {
    const int* x    = (const int*)d_in[0];
    const int* ei   = (const int*)d_in[1];
    const int* ea   = (const int*)d_in[2];
    const int* bat  = (const int*)d_in[3];
    const float* emb0 = (const float*)d_in[4];
    const float* emb1 = (const float*)d_in[5];
    const float* emb2 = (const float*)d_in[6];
    const float* emb3 = (const float*)d_in[7];
    const float* emb4 = (const float*)d_in[8];
    const float* proj_w = (const float*)d_in[9];
    const float* proj_b = (const float*)d_in[10];
    const float* bn_g  = (const float*)d_in[35];
    const float* bn_b  = (const float*)d_in[36];
    const float* bn_rm = (const float*)d_in[37];
    const float* bn_rv = (const float*)d_in[38];
    const float* gate_w = (const float*)d_in[39];
    const float* gate_b = (const float*)d_in[40];
    const float* head_w1 = (const float*)d_in[41];
    const float* head_b1 = (const float*)d_in[42];
    const float* head_w2 = (const float*)d_in[43];
    const float* head_b2 = (const float*)d_in[44];

    char* wsb = (char*)d_ws;
    size_t o = 0;
    auto alloc = [&](size_t bytes) -> void* {
        void* p = wsb + o;
        o += (bytes + 255) & ~(size_t)255;
        return p;
    };
    float* ptab   = (float*)alloc(144 * 64 * 4);
    float* elin   = (float*)alloc(3 * 16 * 64 * 4);
    float* bnsc   = (float*)alloc(64 * 4);
    float* bnsh   = (float*)alloc(64 * 4);
    int* cursor   = (int*)alloc(NBUCK * 4);
    int* gptr     = (int*)alloc((N_GRAPH + 1) * 4);
    int* rowptr   = (int*)alloc(((size_t)N_NODES + 1) * 4);
    int* binned   = (int*)alloc((size_t)NBUCK * BCAP * 4);
    int* epk      = (int*)alloc((size_t)N_EDGES * 4);
    unsigned short* h2a = (unsigned short*)alloc((size_t)N_NODES * 64 * 2);
    unsigned short* h2b = (unsigned short*)alloc((size_t)N_NODES * 64 * 2);
    float* gate   = (float*)alloc((size_t)N_NODES * 4);
    unsigned short* wbf = (unsigned short*)alloc(6 * 4096 * 2);

    k_pre<<<(PRE_JOBS + 255) / 256, 256, 0, stream>>>(
                                  emb0, emb1, emb2, emb3, emb4, proj_w,
                                  (const float*)d_in[11], (const float*)d_in[12], (const float*)d_in[13],
                                  (const float*)d_in[19], (const float*)d_in[20], (const float*)d_in[21],
                                  (const float*)d_in[27], (const float*)d_in[28], (const float*)d_in[29],
                                  bn_g, bn_b, bn_rm, bn_rv,
                                  (const float*)d_in[15], (const float*)d_in[17],
                                  (const float*)d_in[23], (const float*)d_in[25],
                                  (const float*)d_in[31], (const float*)d_in[33],
                                  bat,
                                  ptab, elin, bnsc, bnsh, cursor, wbf, gptr);
    k_binembed<<<NBIN + NEMB, 256, 0, stream>>>(ei, ea, cursor, binned, x, ptab, proj_b, h2a);
    k_fin<<<NBUCK, 256, 0, stream>>>(binned, cursor, rowptr, epk);

    unsigned short* hin = h2a;
    unsigned short* hout = h2b;
    for (int L = 0; L < 3; ++L) {
        const float* epsp = (const float*)d_in[14 + L * 8];
        const float* b1   = (const float*)d_in[16 + L * 8];
        const float* b2   = (const float*)d_in[18 + L * 8];
        const unsigned short* wb1 = wbf + (L * 2 + 0) * 4096;
        const unsigned short* wb2 = wbf + (L * 2 + 1) * 4096;
        if (L < 2) {
            k_gmlp<<<(N_NODES + 63) / 64, 256, 0, stream>>>(hin, elin + L * 1024, rowptr, epk,
                                                            epsp, wb1, b1, wb2, b2, hout,
                                                            nullptr, nullptr, nullptr, nullptr,
                                                            nullptr);
        } else {
            k_gmlp<<<(N_NODES + 63) / 64, 256, 0, stream>>>(hin, elin + L * 1024, rowptr, epk,
                                                            epsp, wb1, b1, wb2, b2, hout,
                                                            bnsc, bnsh, gate_w, gate_b, gate);
        }
        unsigned short* tmp = hin; hin = hout; hout = tmp;
    }

    // after 3 swaps: hin points at the final (layer-3) output buffer
    k_att<<<N_GRAPH, 256, 0, stream>>>(hin, gate, gptr, head_w1, head_b1, head_w2, head_b2,
                                       (float*)d_out);
}